// Round 5
// baseline (174.945 us; speedup 1.0000x reference)
//
#include <hip/hip_runtime.h>

#define D_MODEL 1024
#define NUM_HEADS 16
#define DH 64
#define B_SZ 2
#define T_SZ 2048
#define M_ROWS (B_SZ * T_SZ)   // 4096

typedef __bf16 bf16;
typedef __bf16 bf16x4 __attribute__((ext_vector_type(4)));
typedef __bf16 bf16x8 __attribute__((ext_vector_type(8)));
typedef float f32x4 __attribute__((ext_vector_type(4)));

__device__ __forceinline__ void async_copy16(const bf16* g, bf16* l) {
  __builtin_amdgcn_global_load_lds(
      (const __attribute__((address_space(1))) void*)g,
      (__attribute__((address_space(3))) void*)l, 16, 0, 0);
}

// ---------------------------------------------------------------------------
// 1. Cast fp32 -> bf16
// ---------------------------------------------------------------------------
#define NX (M_ROWS * D_MODEL / 4)
#define NW (D_MODEL * D_MODEL / 4)

__global__ __launch_bounds__(256) void cast_all(
    const float* __restrict__ X, const float* __restrict__ Wq,
    const float* __restrict__ Wk, const float* __restrict__ Wv,
    const float* __restrict__ Wo,
    bf16* __restrict__ Xb, bf16* __restrict__ Wqb, bf16* __restrict__ Wkb,
    bf16* __restrict__ Wvb, bf16* __restrict__ Wob) {
  int i = blockIdx.x * 256 + threadIdx.x;
  const float* s; bf16* d; int off;
  if (i < NX) {
    s = X; d = Xb; off = i;
  } else {
    int j = i - NX;
    int w = j >> 18;
    off = j & (NW - 1);
    if (w == 0)      { s = Wq; d = Wqb; }
    else if (w == 1) { s = Wk; d = Wkb; }
    else if (w == 2) { s = Wv; d = Wvb; }
    else             { s = Wo; d = Wob; }
  }
  float4 v = ((const float4*)s)[off];
  bf16x4 o;
  o[0] = (bf16)v.x; o[1] = (bf16)v.y; o[2] = (bf16)v.z; o[3] = (bf16)v.w;
  ((bf16x4*)d)[off] = o;
}

// ---------------------------------------------------------------------------
// 2. QKV GEMM — 128x256 tile (grid 384 = full CU coverage + 2 blocks/CU),
//    BK=32, 3-deep circular LDS pipeline, counted vmcnt never drained
//    in-loop, one raw barrier per K-tile, setprio MFMA cluster.
//    8 waves (2M x 4N), wave owns 64x64 (4x4 frags). XOR-swizzled LDS via
//    pre-swizzled global source (both-sides involution, proven in R3).
//    Race ledger: iter kt reads buf kt%3 (published by vmcnt(3)+barrier of
//    iter kt-1); issues tile kt+2 into buf (kt+2)%3 whose readers finished
//    before barrier kt-1; waits vmcnt(3) (kt+1's 3 loads = oldest of 6)
//    BEFORE the barrier so next iter's reads are safe on all waves.
//    Fused epilogues: sel==1 K-RoPE on fp32 acc; sel==2 V stored transposed.
// ---------------------------------------------------------------------------
#define KLN 0.28782313662425f   // ln(10000)/32
#define BK 32
#define NKT (D_MODEL / BK)      // 32

__global__ __launch_bounds__(512, 4) void qkv_gemm(
    const bf16* __restrict__ Xb,
    const bf16* __restrict__ Wqb, const bf16* __restrict__ Wkb,
    const bf16* __restrict__ Wvb, const int* __restrict__ pos,
    bf16* __restrict__ Q, bf16* __restrict__ K, bf16* __restrict__ VT) {
  __shared__ bf16 LA[3][128 * BK];     // 3 x 8 KB
  __shared__ bf16 LB[3][256 * BK];     // 3 x 16 KB  (72 KB total)

  int tid = threadIdx.x;
  int wave = tid >> 6, lane = tid & 63;
  int wm = wave >> 2, wn = wave & 3;   // 2 x 4 wave grid
  int l15 = lane & 15, quad = lane >> 4;

  int row0 = blockIdx.x * 128;
  int col0 = blockIdx.y * 256;
  int sel = col0 >> 10;
  int nb = col0 & 1023;
  const bf16* W = (sel == 0) ? Wqb : (sel == 1) ? Wkb : Wvb;

  // staging: A row tid>>2 (1 copy); B rows tid>>2 and +128 (2 copies).
  // source column pre-swizzled so linear LDS == swizzled layout
  int srow = tid >> 2;
  int scol = 8 * ((tid & 3) ^ ((tid >> 3) & 3));
  const bf16* Ag = Xb + (size_t)(row0 + srow) * D_MODEL + scol;
  const bf16* Bg = W + (size_t)(nb + srow) * D_MODEL + scol;
  int ldst = tid * 8;

  int swz = 8 * (quad ^ ((l15 >> 1) & 3));
  int aoff = (wm * 64 + l15) * BK + swz;
  int boff = (wn * 64 + l15) * BK + swz;

  f32x4 acc[4][4];
#pragma unroll
  for (int mi = 0; mi < 4; ++mi)
#pragma unroll
    for (int nj = 0; nj < 4; ++nj) acc[mi][nj] = (f32x4){0.f, 0.f, 0.f, 0.f};

#define STAGE(bq, pt)                                                        \
  do {                                                                       \
    int k0_ = (pt) * BK;                                                     \
    async_copy16(Ag + k0_, &LA[bq][ldst]);                                   \
    async_copy16(Bg + k0_, &LB[bq][ldst]);                                   \
    async_copy16(Bg + k0_ + (size_t)128 * D_MODEL, &LB[bq][ldst + 4096]);    \
  } while (0)

  // prologue: stage tiles 0,1; wait tile 0 (oldest 3 of 6)
  STAGE(0, 0);
  STAGE(1, 1);
  asm volatile("s_waitcnt vmcnt(3)" ::: "memory");
  __builtin_amdgcn_s_barrier();
  __builtin_amdgcn_sched_barrier(0);

  int cur = 0;                         // kt % 3
  for (int kt = 0; kt < NKT; ++kt) {
    const bf16* La = LA[cur];
    const bf16* Lb = LB[cur];
    bf16x8 a[4], b[4];
#pragma unroll
    for (int mi = 0; mi < 4; ++mi)
      a[mi] = *(const bf16x8*)&La[aoff + mi * 16 * BK];
#pragma unroll
    for (int nj = 0; nj < 4; ++nj)
      b[nj] = *(const bf16x8*)&Lb[boff + nj * 16 * BK];

    if (kt + 2 < NKT) {                // stage tile kt+2 into buf (kt+2)%3
      int nbuf = cur + 2 >= 3 ? cur - 1 : cur + 2;
      STAGE(nbuf, kt + 2);
      asm volatile("s_waitcnt vmcnt(3) lgkmcnt(0)" ::: "memory");
    } else {
      asm volatile("s_waitcnt vmcnt(0) lgkmcnt(0)" ::: "memory");
    }
    __builtin_amdgcn_s_barrier();
    __builtin_amdgcn_sched_barrier(0);

    __builtin_amdgcn_s_setprio(1);
#pragma unroll
    for (int mi = 0; mi < 4; ++mi)
#pragma unroll
      for (int nj = 0; nj < 4; ++nj)
        acc[mi][nj] = __builtin_amdgcn_mfma_f32_16x16x32_bf16(
            a[mi], b[nj], acc[mi][nj], 0, 0, 0);
    __builtin_amdgcn_s_setprio(0);

    cur = cur == 2 ? 0 : cur + 1;
  }
#undef STAGE

  // ---- epilogues ----
  if (sel == 1) {
    // fused K-RoPE on fp32 accumulator; pairs are adjacent lanes (cols)
    bool even = (l15 & 1) == 0;
#pragma unroll
    for (int nj = 0; nj < 4; ++nj) {
      float fr = __expf(-(float)((nj * 16 + (l15 & 14)) >> 1) * KLN);
#pragma unroll
      for (int mi = 0; mi < 4; ++mi)
#pragma unroll
        for (int r = 0; r < 4; ++r) {
          float p = (float)pos[(row0 + wm * 64 + mi * 16 + quad * 4 + r) &
                               (T_SZ - 1)];
          float v = acc[mi][nj][r];
          float pn = __shfl_xor(v, 1);
          float s, c;
          __sincosf(p * fr, &s, &c);
          acc[mi][nj][r] = even ? (v * c - pn * s) : (pn * s + v * c);
        }
    }
  }

  if (sel == 2) {
    // V stored directly transposed: VT[(b*16+h)*64+d][t], r packs along t
    int b = row0 >> 11;
    int t0 = row0 & (T_SZ - 1);
#pragma unroll
    for (int mi = 0; mi < 4; ++mi) {
      int t = t0 + wm * 64 + mi * 16 + quad * 4;
#pragma unroll
      for (int nj = 0; nj < 4; ++nj) {
        int col = nb + wn * 64 + nj * 16 + l15;
        int h = col >> 6;
        int d = col & 63;
        bf16x4 ov;
#pragma unroll
        for (int r = 0; r < 4; ++r) ov[r] = (bf16)acc[mi][nj][r];
        *(bf16x4*)&VT[((size_t)(b * NUM_HEADS + h) * DH + d) * T_SZ + t] = ov;
      }
    }
  } else {
    bf16* Out = (sel == 0) ? Q : K;
#pragma unroll
    for (int mi = 0; mi < 4; ++mi) {
      int row = row0 + wm * 64 + mi * 16 + quad * 4;
#pragma unroll
      for (int nj = 0; nj < 4; ++nj) {
        int col = nb + wn * 64 + nj * 16 + l15;
#pragma unroll
        for (int r = 0; r < 4; ++r)
          Out[(size_t)(row + r) * D_MODEL + col] = (bf16)acc[mi][nj][r];
      }
    }
  }
}

// ---------------------------------------------------------------------------
// 3. Causal flash attention (verified structure) + CU-balanced qi remap:
//    qi(y) chosen so each CU-group's four q-tiles sum to 66 chunks
//    (was 80-4g with the monotone heavy-first map -> +-21% makespan skew).
// ---------------------------------------------------------------------------
#define PST 72
#define KST 72

__global__ __launch_bounds__(256) void attn_kernel(
    const bf16* __restrict__ Q, const bf16* __restrict__ K,
    const bf16* __restrict__ VT, const int* __restrict__ pos,
    bf16* __restrict__ AO) {
  __shared__ bf16 Kt[64 * KST];          // K rows (kv), d 0..63, stride 72
  __shared__ bf16 Vt[64 * KST];          // VT rows (d), c 0..63, stride 72
  __shared__ bf16 Pbuf[4][16 * PST];

  int bh = blockIdx.x;                   // 0..31
  int y = blockIdx.y;
  int yq = y >> 3, yr = y & 7;
  int qi = 8 * yq + ((yq & 1) ? 7 - yr : yr);  // balanced bijection
  int bb = bh >> 4, h = bh & 15;
  int tid = threadIdx.x;
  int wave = tid >> 6, lane = tid & 63;
  int l15 = lane & 15, quad = lane >> 4;

  int q0 = qi * 64 + wave * 16;
  size_t grow = (size_t)bb * T_SZ + q0;

  // ---- Q fragments + in-register RoPE (pairs are in-lane) ----
  const bf16* Qp = Q + (grow + l15) * D_MODEL + h * DH + quad * 8;
  bf16x8 bq0 = *(const bf16x8*)(Qp);
  bf16x8 bq1 = *(const bf16x8*)(Qp + 32);
  {
    float p = (float)pos[q0 + l15];
#pragma unroll
    for (int jj = 0; jj < 4; ++jj) {
      int i0 = quad * 4 + jj;
      float s, c;
      __sincosf(p * __expf(-(float)i0 * KLN), &s, &c);
      float x1 = (float)bq0[2 * jj], x2 = (float)bq0[2 * jj + 1];
      bq0[2 * jj]     = (bf16)(x1 * c - x2 * s);
      bq0[2 * jj + 1] = (bf16)(x1 * s + x2 * c);
      __sincosf(p * __expf(-(float)(i0 + 16) * KLN), &s, &c);
      float y1 = (float)bq1[2 * jj], y2 = (float)bq1[2 * jj + 1];
      bq1[2 * jj]     = (bf16)(y1 * c - y2 * s);
      bq1[2 * jj + 1] = (bf16)(y1 * s + y2 * c);
    }
  }

  f32x4 o[4];
#pragma unroll
  for (int nt = 0; nt < 4; ++nt) o[nt] = (f32x4){0.f, 0.f, 0.f, 0.f};
  float l_i = 0.f;

  // ---- staging: thread covers K row tid>>2 (16 d-elems) + same for VT ----
  int srow = tid >> 2;                   // 0..63
  int sc = (tid & 3) * 16;               // elem col base (32 B per thread)
  const bf16* Kg = K + ((size_t)bb * T_SZ + srow) * D_MODEL + h * DH + sc;
  const bf16* Vg = VT + ((size_t)bh * DH + srow) * T_SZ + sc;
  bf16* Kl = &Kt[srow * KST + sc];
  bf16* Vl = &Vt[srow * KST + sc];

  bf16* Pw = Pbuf[wave];
  int nchunks = qi + 1;
  int rel = wave * 16 + l15;             // causal boundary (last chunk)

  // prefetch chunk 0
  bf16x8 kr0 = *(const bf16x8*)(Kg);
  bf16x8 kr1 = *(const bf16x8*)(Kg + 8);
  bf16x8 vr0 = *(const bf16x8*)(Vg);
  bf16x8 vr1 = *(const bf16x8*)(Vg + 8);

  for (int t = 0; t < nchunks; ++t) {
    __syncthreads();                     // previous compute done; LDS writable
    *(bf16x8*)(Kl) = kr0;
    *(bf16x8*)(Kl + 8) = kr1;
    *(bf16x8*)(Vl) = vr0;
    *(bf16x8*)(Vl + 8) = vr1;
    if (t + 1 < nchunks) {               // prefetch next chunk into registers
      const bf16* Kn = Kg + (size_t)(t + 1) * 64 * D_MODEL;
      const bf16* Vn = Vg + (t + 1) * 64;
      kr0 = *(const bf16x8*)(Kn);
      kr1 = *(const bf16x8*)(Kn + 8);
      vr0 = *(const bf16x8*)(Vn);
      vr1 = *(const bf16x8*)(Vn + 8);
    }
    __syncthreads();                     // tiles ready

    // ---- S^T = K · Q^T ----
    f32x4 st[4];
#pragma unroll
    for (int cs = 0; cs < 4; ++cs) {
      bf16x8 ak0 = *(const bf16x8*)&Kt[(cs * 16 + l15) * KST + quad * 8];
      bf16x8 ak1 = *(const bf16x8*)&Kt[(cs * 16 + l15) * KST + 32 + quad * 8];
      f32x4 s4 = (f32x4){0.f, 0.f, 0.f, 0.f};
      s4 = __builtin_amdgcn_mfma_f32_16x16x32_bf16(ak0, bq0, s4, 0, 0, 0);
      s4 = __builtin_amdgcn_mfma_f32_16x16x32_bf16(ak1, bq1, s4, 0, 0, 0);
      st[cs] = s4;
    }

    // ---- p = exp(s*scale); mask above diagonal on last chunk ----
    bool last = (t == nchunks - 1);
    float ps = 0.f;
#pragma unroll
    for (int cs = 0; cs < 4; ++cs)
#pragma unroll
      for (int r = 0; r < 4; ++r) {
        float p = __expf(st[cs][r] * 0.125f);
        if (last) {
          int cl = cs * 16 + quad * 4 + r;
          p = (cl > rel) ? 0.f : p;
        }
        st[cs][r] = p;
        ps += p;
      }
    l_i += ps;

    // ---- P[q][c] -> per-wave LDS, transpose to B-operand layout ----
#pragma unroll
    for (int cs = 0; cs < 4; ++cs) {
      bf16x4 pk;
#pragma unroll
      for (int r = 0; r < 4; ++r) pk[r] = (bf16)st[cs][r];
      *(bf16x4*)&Pw[l15 * PST + cs * 16 + quad * 4] = pk;
    }
    __asm__ __volatile__("" ::: "memory");
    bf16x8 bp0 = *(const bf16x8*)&Pw[l15 * PST + quad * 8];
    bf16x8 bp1 = *(const bf16x8*)&Pw[l15 * PST + 32 + quad * 8];
    __asm__ __volatile__("" ::: "memory");

    // ---- O^T += V^T · P^T ----
#pragma unroll
    for (int nt = 0; nt < 4; ++nt) {
      bf16x8 av0 = *(const bf16x8*)&Vt[(nt * 16 + l15) * KST + quad * 8];
      bf16x8 av1 = *(const bf16x8*)&Vt[(nt * 16 + l15) * KST + 32 + quad * 8];
      o[nt] = __builtin_amdgcn_mfma_f32_16x16x32_bf16(av0, bp0, o[nt], 0, 0, 0);
      o[nt] = __builtin_amdgcn_mfma_f32_16x16x32_bf16(av1, bp1, o[nt], 0, 0, 0);
    }
  }

  // ---- l reduction across quads, normalize, store ----
  l_i += __shfl_xor(l_i, 16);
  l_i += __shfl_xor(l_i, 32);
  float inv = 1.0f / l_i;
#pragma unroll
  for (int nt = 0; nt < 4; ++nt) {
    bf16x4 ov;
#pragma unroll
    for (int r = 0; r < 4; ++r) ov[r] = (bf16)(o[nt][r] * inv);
    *(bf16x4*)&AO[(grow + l15) * D_MODEL + h * DH + nt * 16 + quad * 4] = ov;
  }
}

// ---------------------------------------------------------------------------
// 4. Output GEMM: 128x64 tiles -> 512 blocks (2/CU)
// ---------------------------------------------------------------------------
__global__ __launch_bounds__(256) void out_gemm(
    const bf16* __restrict__ AO, const bf16* __restrict__ Wob,
    float* __restrict__ out) {
  __shared__ bf16 As[128 * 32];
  __shared__ bf16 Bs[64 * 32];

  int tid = threadIdx.x;
  int wave = tid >> 6, lane = tid & 63;
  int l15 = lane & 15, quad = lane >> 4;

  int row0 = blockIdx.x * 128;
  int nb = blockIdx.y * 64;

  int srow = tid >> 2;
  int schunk = tid & 3;
  const bf16* Ag = AO + (size_t)(row0 + srow) * D_MODEL + schunk * 8;
  const bf16* Bg = Wob + (size_t)(nb + srow) * D_MODEL + schunk * 8;
  bf16* Al0 = &As[srow * 32 + schunk * 8];
  bf16* Al1 = &As[(srow + 64) * 32 + schunk * 8];
  bf16* Bl = &Bs[srow * 32 + schunk * 8];

  f32x4 acc[2][4];
#pragma unroll
  for (int i = 0; i < 2; ++i)
#pragma unroll
    for (int j = 0; j < 4; ++j) acc[i][j] = (f32x4){0.f, 0.f, 0.f, 0.f};

  for (int k0 = 0; k0 < D_MODEL; k0 += 32) {
    async_copy16(Ag + k0, Al0);
    async_copy16(Ag + k0 + (size_t)64 * D_MODEL, Al1);
    async_copy16(Bg + k0, Bl);
    __syncthreads();

    bf16x8 af[2], bfr[4];
#pragma unroll
    for (int i = 0; i < 2; ++i)
      af[i] = *(const bf16x8*)&As[(wave * 32 + i * 16 + l15) * 32 + quad * 8];
#pragma unroll
    for (int j = 0; j < 4; ++j)
      bfr[j] = *(const bf16x8*)&Bs[(j * 16 + l15) * 32 + quad * 8];
#pragma unroll
    for (int i = 0; i < 2; ++i)
#pragma unroll
      for (int j = 0; j < 4; ++j)
        acc[i][j] = __builtin_amdgcn_mfma_f32_16x16x32_bf16(af[i], bfr[j],
                                                            acc[i][j], 0, 0, 0);
    __syncthreads();
  }

#pragma unroll
  for (int i = 0; i < 2; ++i) {
    int row = row0 + wave * 32 + i * 16 + quad * 4;
#pragma unroll
    for (int j = 0; j < 4; ++j) {
      int col = nb + j * 16 + l15;
#pragma unroll
      for (int r = 0; r < 4; ++r)
        out[(size_t)(row + r) * D_MODEL + col] = acc[i][j][r];
    }
  }
}

// ---------------------------------------------------------------------------
extern "C" void kernel_launch(void* const* d_in, const int* in_sizes, int n_in,
                              void* d_out, int out_size, void* d_ws, size_t ws_size,
                              hipStream_t stream) {
  const float* X  = (const float*)d_in[0];
  const float* Wq = (const float*)d_in[1];
  const float* Wk = (const float*)d_in[2];
  const float* Wv = (const float*)d_in[3];
  const float* Wo = (const float*)d_in[4];
  const int*  pos = (const int*)d_in[5];
  float* out = (float*)d_out;

  char* w = (char*)d_ws;
  bf16* Xb  = (bf16*)w;  w += (size_t)M_ROWS * D_MODEL * 2;
  bf16* Wqb = (bf16*)w;  w += (size_t)D_MODEL * D_MODEL * 2;
  bf16* Wkb = (bf16*)w;  w += (size_t)D_MODEL * D_MODEL * 2;
  bf16* Wvb = (bf16*)w;  w += (size_t)D_MODEL * D_MODEL * 2;
  bf16* Wob = (bf16*)w;  w += (size_t)D_MODEL * D_MODEL * 2;
  bf16* Qb  = (bf16*)w;  w += (size_t)M_ROWS * D_MODEL * 2;
  bf16* Kb  = (bf16*)w;  w += (size_t)M_ROWS * D_MODEL * 2;
  bf16* VT  = (bf16*)w;  w += (size_t)M_ROWS * D_MODEL * 2;
  bf16* AO  = (bf16*)w;  w += (size_t)M_ROWS * D_MODEL * 2;

  cast_all<<<(NX + 4 * NW) / 256, 256, 0, stream>>>(X, Wq, Wk, Wv, Wo,
                                                    Xb, Wqb, Wkb, Wvb, Wob);
  qkv_gemm<<<dim3(M_ROWS / 128, 3 * D_MODEL / 256), 512, 0, stream>>>(
      Xb, Wqb, Wkb, Wvb, pos, Qb, Kb, VT);
  attn_kernel<<<dim3(B_SZ * NUM_HEADS, T_SZ / 64), 256, 0, stream>>>(
      Qb, Kb, VT, pos, AO);
  out_gemm<<<dim3(M_ROWS / 128, D_MODEL / 64), 256, 0, stream>>>(AO, Wob, out);
}

// Round 6
// 173.041 us; speedup vs baseline: 1.0110x; 1.0110x over previous
//
#include <hip/hip_runtime.h>

#define D_MODEL 1024
#define NUM_HEADS 16
#define DH 64
#define B_SZ 2
#define T_SZ 2048
#define M_ROWS (B_SZ * T_SZ)   // 4096

typedef __bf16 bf16;
typedef __bf16 bf16x4 __attribute__((ext_vector_type(4)));
typedef __bf16 bf16x8 __attribute__((ext_vector_type(8)));
typedef float f32x4 __attribute__((ext_vector_type(4)));

__device__ __forceinline__ void async_copy16(const bf16* g, bf16* l) {
  __builtin_amdgcn_global_load_lds(
      (const __attribute__((address_space(1))) void*)g,
      (__attribute__((address_space(3))) void*)l, 16, 0, 0);
}

// ---------------------------------------------------------------------------
// 1. Cast fp32 -> bf16
// ---------------------------------------------------------------------------
#define NX (M_ROWS * D_MODEL / 4)
#define NW (D_MODEL * D_MODEL / 4)

__global__ __launch_bounds__(256) void cast_all(
    const float* __restrict__ X, const float* __restrict__ Wq,
    const float* __restrict__ Wk, const float* __restrict__ Wv,
    const float* __restrict__ Wo,
    bf16* __restrict__ Xb, bf16* __restrict__ Wqb, bf16* __restrict__ Wkb,
    bf16* __restrict__ Wvb, bf16* __restrict__ Wob) {
  int i = blockIdx.x * 256 + threadIdx.x;
  const float* s; bf16* d; int off;
  if (i < NX) {
    s = X; d = Xb; off = i;
  } else {
    int j = i - NX;
    int w = j >> 18;
    off = j & (NW - 1);
    if (w == 0)      { s = Wq; d = Wqb; }
    else if (w == 1) { s = Wk; d = Wkb; }
    else if (w == 2) { s = Wv; d = Wvb; }
    else             { s = Wo; d = Wob; }
  }
  float4 v = ((const float4*)s)[off];
  bf16x4 o;
  o[0] = (bf16)v.x; o[1] = (bf16)v.y; o[2] = (bf16)v.z; o[3] = (bf16)v.w;
  ((bf16x4*)d)[off] = o;
}

// ---------------------------------------------------------------------------
// 2. QKV GEMM — 128x256 tile, BK=32, 3-deep circular LDS pipeline (R4, kept).
// ---------------------------------------------------------------------------
#define KLN 0.28782313662425f   // ln(10000)/32
#define BK 32
#define NKT (D_MODEL / BK)      // 32

__global__ __launch_bounds__(512, 4) void qkv_gemm(
    const bf16* __restrict__ Xb,
    const bf16* __restrict__ Wqb, const bf16* __restrict__ Wkb,
    const bf16* __restrict__ Wvb, const int* __restrict__ pos,
    bf16* __restrict__ Q, bf16* __restrict__ K, bf16* __restrict__ VT) {
  __shared__ bf16 LA[3][128 * BK];     // 3 x 8 KB
  __shared__ bf16 LB[3][256 * BK];     // 3 x 16 KB  (72 KB total)

  int tid = threadIdx.x;
  int wave = tid >> 6, lane = tid & 63;
  int wm = wave >> 2, wn = wave & 3;   // 2 x 4 wave grid
  int l15 = lane & 15, quad = lane >> 4;

  int row0 = blockIdx.x * 128;
  int col0 = blockIdx.y * 256;
  int sel = col0 >> 10;
  int nb = col0 & 1023;
  const bf16* W = (sel == 0) ? Wqb : (sel == 1) ? Wkb : Wvb;

  int srow = tid >> 2;
  int scol = 8 * ((tid & 3) ^ ((tid >> 3) & 3));
  const bf16* Ag = Xb + (size_t)(row0 + srow) * D_MODEL + scol;
  const bf16* Bg = W + (size_t)(nb + srow) * D_MODEL + scol;
  int ldst = tid * 8;

  int swz = 8 * (quad ^ ((l15 >> 1) & 3));
  int aoff = (wm * 64 + l15) * BK + swz;
  int boff = (wn * 64 + l15) * BK + swz;

  f32x4 acc[4][4];
#pragma unroll
  for (int mi = 0; mi < 4; ++mi)
#pragma unroll
    for (int nj = 0; nj < 4; ++nj) acc[mi][nj] = (f32x4){0.f, 0.f, 0.f, 0.f};

#define STAGE(bq, pt)                                                        \
  do {                                                                       \
    int k0_ = (pt) * BK;                                                     \
    async_copy16(Ag + k0_, &LA[bq][ldst]);                                   \
    async_copy16(Bg + k0_, &LB[bq][ldst]);                                   \
    async_copy16(Bg + k0_ + (size_t)128 * D_MODEL, &LB[bq][ldst + 4096]);    \
  } while (0)

  STAGE(0, 0);
  STAGE(1, 1);
  asm volatile("s_waitcnt vmcnt(3)" ::: "memory");
  __builtin_amdgcn_s_barrier();
  __builtin_amdgcn_sched_barrier(0);

  int cur = 0;                         // kt % 3
  for (int kt = 0; kt < NKT; ++kt) {
    const bf16* La = LA[cur];
    const bf16* Lb = LB[cur];
    bf16x8 a[4], b[4];
#pragma unroll
    for (int mi = 0; mi < 4; ++mi)
      a[mi] = *(const bf16x8*)&La[aoff + mi * 16 * BK];
#pragma unroll
    for (int nj = 0; nj < 4; ++nj)
      b[nj] = *(const bf16x8*)&Lb[boff + nj * 16 * BK];

    if (kt + 2 < NKT) {                // stage tile kt+2 into buf (kt+2)%3
      int nbuf = cur + 2 >= 3 ? cur - 1 : cur + 2;
      STAGE(nbuf, kt + 2);
      asm volatile("s_waitcnt vmcnt(3) lgkmcnt(0)" ::: "memory");
    } else {
      asm volatile("s_waitcnt vmcnt(0) lgkmcnt(0)" ::: "memory");
    }
    __builtin_amdgcn_s_barrier();
    __builtin_amdgcn_sched_barrier(0);

    __builtin_amdgcn_s_setprio(1);
#pragma unroll
    for (int mi = 0; mi < 4; ++mi)
#pragma unroll
      for (int nj = 0; nj < 4; ++nj)
        acc[mi][nj] = __builtin_amdgcn_mfma_f32_16x16x32_bf16(
            a[mi], b[nj], acc[mi][nj], 0, 0, 0);
    __builtin_amdgcn_s_setprio(0);

    cur = cur == 2 ? 0 : cur + 1;
  }
#undef STAGE

  // ---- epilogues ----
  if (sel == 1) {
    bool even = (l15 & 1) == 0;
#pragma unroll
    for (int nj = 0; nj < 4; ++nj) {
      float fr = __expf(-(float)((nj * 16 + (l15 & 14)) >> 1) * KLN);
#pragma unroll
      for (int mi = 0; mi < 4; ++mi)
#pragma unroll
        for (int r = 0; r < 4; ++r) {
          float p = (float)pos[(row0 + wm * 64 + mi * 16 + quad * 4 + r) &
                               (T_SZ - 1)];
          float v = acc[mi][nj][r];
          float pn = __shfl_xor(v, 1);
          float s, c;
          __sincosf(p * fr, &s, &c);
          acc[mi][nj][r] = even ? (v * c - pn * s) : (pn * s + v * c);
        }
    }
  }

  if (sel == 2) {
    int b = row0 >> 11;
    int t0 = row0 & (T_SZ - 1);
#pragma unroll
    for (int mi = 0; mi < 4; ++mi) {
      int t = t0 + wm * 64 + mi * 16 + quad * 4;
#pragma unroll
      for (int nj = 0; nj < 4; ++nj) {
        int col = nb + wn * 64 + nj * 16 + l15;
        int h = col >> 6;
        int d = col & 63;
        bf16x4 ov;
#pragma unroll
        for (int r = 0; r < 4; ++r) ov[r] = (bf16)acc[mi][nj][r];
        *(bf16x4*)&VT[((size_t)(b * NUM_HEADS + h) * DH + d) * T_SZ + t] = ov;
      }
    }
  } else {
    bf16* Out = (sel == 0) ? Q : K;
#pragma unroll
    for (int mi = 0; mi < 4; ++mi) {
      int row = row0 + wm * 64 + mi * 16 + quad * 4;
#pragma unroll
      for (int nj = 0; nj < 4; ++nj) {
        int col = nb + wn * 64 + nj * 16 + l15;
#pragma unroll
        for (int r = 0; r < 4; ++r)
          Out[(size_t)(row + r) * D_MODEL + col] = (bf16)acc[mi][nj][r];
      }
    }
  }
}

// ---------------------------------------------------------------------------
// 3. Causal flash attention — kv-split waves (LDS-traffic fix).
//    Wave w owns kv rows [w*16, w*16+16) of each 64-chunk and computes a
//    PARTIAL O over all 64 q rows. LDS reads per wave per chunk: 2 b128 (K)
//    + 4 b64 (V) vs previous 16 b128 + P round-trip (DS pipe was ~85% busy).
//    P feeds PV entirely in-lane: QK^T C-layout (row=kv=quad*4+r) equals the
//    A-operand layout of v_mfma_f32_16x16x16_bf16 (k=quad*4+j). PV B = VT
//    rows from LDS (b64). Partial O (64 VGPR/wave) reduced across waves via
//    a 3-step LDS rotation reusing the K/V buffers; wave w ends owning
//    q-subtile w and stores it.
// ---------------------------------------------------------------------------
#define KST 72

__global__ __launch_bounds__(256, 3) void attn_kernel(
    const bf16* __restrict__ Q, const bf16* __restrict__ K,
    const bf16* __restrict__ VT, const int* __restrict__ pos,
    bf16* __restrict__ AO) {
  __shared__ bf16 KV[2 * 64 * KST];      // Kt | Vt ; reused as f32 red (16KB)
  __shared__ float lred[4][4][16];
  bf16* Kt = KV;
  bf16* Vt = KV + 64 * KST;

  int bh = blockIdx.x;                   // 0..31
  int qi = 31 - (int)blockIdx.y;         // q-tile of 64, heavy first
  int bb = bh >> 4, h = bh & 15;
  int tid = threadIdx.x;
  int wave = tid >> 6, lane = tid & 63;
  int l15 = lane & 15, quad = lane >> 4;
  int w16 = wave * 16;

  int q0 = qi * 64;
  size_t grow = (size_t)bb * T_SZ + q0;

  // ---- Q fragments for ALL 4 q-subtiles + in-register RoPE ----
  bf16x8 bq[4][2];
#pragma unroll
  for (int qt = 0; qt < 4; ++qt) {
    const bf16* Qp = Q + (grow + qt * 16 + l15) * D_MODEL + h * DH + quad * 8;
    bq[qt][0] = *(const bf16x8*)(Qp);
    bq[qt][1] = *(const bf16x8*)(Qp + 32);
    float p = (float)pos[q0 + qt * 16 + l15];
#pragma unroll
    for (int jj = 0; jj < 4; ++jj) {
      int i0 = quad * 4 + jj;
      float s, c;
      __sincosf(p * __expf(-(float)i0 * KLN), &s, &c);
      float x1 = (float)bq[qt][0][2 * jj], x2 = (float)bq[qt][0][2 * jj + 1];
      bq[qt][0][2 * jj]     = (bf16)(x1 * c - x2 * s);
      bq[qt][0][2 * jj + 1] = (bf16)(x1 * s + x2 * c);
      __sincosf(p * __expf(-(float)(i0 + 16) * KLN), &s, &c);
      float y1 = (float)bq[qt][1][2 * jj], y2 = (float)bq[qt][1][2 * jj + 1];
      bq[qt][1][2 * jj]     = (bf16)(y1 * c - y2 * s);
      bq[qt][1][2 * jj + 1] = (bf16)(y1 * s + y2 * c);
    }
  }

  f32x4 o[4][4];                         // [dt][qt] partial O, 64 VGPR
#pragma unroll
  for (int dt = 0; dt < 4; ++dt)
#pragma unroll
    for (int qt = 0; qt < 4; ++qt) o[dt][qt] = (f32x4){0.f, 0.f, 0.f, 0.f};
  float l_acc[4] = {0.f, 0.f, 0.f, 0.f};

  // ---- staging (unchanged): thread covers K row tid>>2 + same for VT ----
  int srow = tid >> 2;                   // 0..63
  int sc = (tid & 3) * 16;               // elem col base (32 B per thread)
  const bf16* Kg = K + ((size_t)bb * T_SZ + srow) * D_MODEL + h * DH + sc;
  const bf16* Vg = VT + ((size_t)bh * DH + srow) * T_SZ + sc;
  bf16* Kl = &Kt[srow * KST + sc];
  bf16* Vl = &Vt[srow * KST + sc];

  int nchunks = qi + 1;

  // prefetch chunk 0
  bf16x8 kr0 = *(const bf16x8*)(Kg);
  bf16x8 kr1 = *(const bf16x8*)(Kg + 8);
  bf16x8 vr0 = *(const bf16x8*)(Vg);
  bf16x8 vr1 = *(const bf16x8*)(Vg + 8);

  for (int t = 0; t < nchunks; ++t) {
    __syncthreads();                     // previous compute done; LDS writable
    *(bf16x8*)(Kl) = kr0;
    *(bf16x8*)(Kl + 8) = kr1;
    *(bf16x8*)(Vl) = vr0;
    *(bf16x8*)(Vl + 8) = vr1;
    if (t + 1 < nchunks) {               // prefetch next chunk into registers
      const bf16* Kn = Kg + (size_t)(t + 1) * 64 * D_MODEL;
      const bf16* Vn = Vg + (t + 1) * 64;
      kr0 = *(const bf16x8*)(Kn);
      kr1 = *(const bf16x8*)(Kn + 8);
      vr0 = *(const bf16x8*)(Vn);
      vr1 = *(const bf16x8*)(Vn + 8);
    }
    __syncthreads();                     // tiles ready

    // ---- S^T (this wave's 16 kv rows x 64 q) = K_w · Q^T ----
    bf16x8 ak0 = *(const bf16x8*)&Kt[(w16 + l15) * KST + quad * 8];
    bf16x8 ak1 = *(const bf16x8*)&Kt[(w16 + l15) * KST + 32 + quad * 8];
    f32x4 st[4];
#pragma unroll
    for (int qt = 0; qt < 4; ++qt) {
      f32x4 s4 = (f32x4){0.f, 0.f, 0.f, 0.f};
      s4 = __builtin_amdgcn_mfma_f32_16x16x32_bf16(ak0, bq[qt][0], s4, 0, 0, 0);
      s4 = __builtin_amdgcn_mfma_f32_16x16x32_bf16(ak1, bq[qt][1], s4, 0, 0, 0);
      st[qt] = s4;
    }

    // ---- p = exp(s*scale); causal mask on last chunk; pack bf16 in-lane ----
    bool last = (t == nchunks - 1);
    bf16x4 pb[4];
#pragma unroll
    for (int qt = 0; qt < 4; ++qt) {
      float ps = 0.f;
#pragma unroll
      for (int j = 0; j < 4; ++j) {
        float p = __expf(st[qt][j] * 0.125f);
        if (last) {
          int cl = w16 + quad * 4 + j;   // kv within chunk
          p = (cl > qt * 16 + l15) ? 0.f : p;
        }
        pb[qt][j] = (bf16)p;
        ps += p;
      }
      l_acc[qt] += ps;
    }

    // ---- partial O[q][d] += P_w · V_w  (A=P in-lane, B=VT rows from LDS) ----
#pragma unroll
    for (int dt = 0; dt < 4; ++dt) {
      bf16x4 vb = *(const bf16x4*)&Vt[(dt * 16 + l15) * KST + w16 + quad * 4];
#pragma unroll
      for (int qt = 0; qt < 4; ++qt)
        asm("v_mfma_f32_16x16x16_bf16 %0, %1, %2, %0"
            : "+v"(o[dt][qt])
            : "v"(pb[qt]), "v"(vb));
    }
  }

  // ---- l: in-wave quad reduction, publish per-wave sums ----
#pragma unroll
  for (int qt = 0; qt < 4; ++qt) {
    l_acc[qt] += __shfl_xor(l_acc[qt], 16);
    l_acc[qt] += __shfl_xor(l_acc[qt], 32);
  }
  if (lane < 16) {
#pragma unroll
    for (int qt = 0; qt < 4; ++qt) lred[wave][qt][lane] = l_acc[qt];
  }

  __syncthreads();                       // loop LDS dead; red reusable
  float* red = (float*)KV;               // 16 KB scratch

  // ---- 3-step rotate-reduce: wave w ends owning q-subtile w ----
#pragma unroll
  for (int s = 1; s <= 3; ++s) {
#pragma unroll
    for (int qt = 0; qt < 4; ++qt)
      if (((qt - s) & 3) == wave) {
#pragma unroll
        for (int dt = 0; dt < 4; ++dt)
          *(f32x4*)&red[qt * 1024 + dt * 256 + lane * 4] = o[dt][qt];
      }
    __syncthreads();
#pragma unroll
    for (int qt = 0; qt < 4; ++qt)
      if (qt == wave) {
#pragma unroll
        for (int dt = 0; dt < 4; ++dt)
          o[dt][qt] += *(const f32x4*)&red[qt * 1024 + dt * 256 + lane * 4];
      }
    __syncthreads();
  }

  // ---- normalize + store (wave w stores q-subtile w) ----
#pragma unroll
  for (int qt = 0; qt < 4; ++qt)
    if (qt == wave) {
      float inv[4];
#pragma unroll
      for (int r = 0; r < 4; ++r) {
        int qq = quad * 4 + r;
        float ls = lred[0][qt][qq] + lred[1][qt][qq] + lred[2][qt][qq] +
                   lred[3][qt][qq];
        inv[r] = 1.0f / ls;
      }
#pragma unroll
      for (int dt = 0; dt < 4; ++dt)
#pragma unroll
        for (int r = 0; r < 4; ++r)
          AO[(grow + qt * 16 + quad * 4 + r) * D_MODEL + h * DH + dt * 16 +
             l15] = (bf16)(o[dt][qt][r] * inv[r]);
    }
}

// ---------------------------------------------------------------------------
// 4. Output GEMM: 128x64 tiles -> 512 blocks (2/CU)
// ---------------------------------------------------------------------------
__global__ __launch_bounds__(256) void out_gemm(
    const bf16* __restrict__ AO, const bf16* __restrict__ Wob,
    float* __restrict__ out) {
  __shared__ bf16 As[128 * 32];
  __shared__ bf16 Bs[64 * 32];

  int tid = threadIdx.x;
  int wave = tid >> 6, lane = tid & 63;
  int l15 = lane & 15, quad = lane >> 4;

  int row0 = blockIdx.x * 128;
  int nb = blockIdx.y * 64;

  int srow = tid >> 2;
  int schunk = tid & 3;
  const bf16* Ag = AO + (size_t)(row0 + srow) * D_MODEL + schunk * 8;
  const bf16* Bg = Wob + (size_t)(nb + srow) * D_MODEL + schunk * 8;
  bf16* Al0 = &As[srow * 32 + schunk * 8];
  bf16* Al1 = &As[(srow + 64) * 32 + schunk * 8];
  bf16* Bl = &Bs[srow * 32 + schunk * 8];

  f32x4 acc[2][4];
#pragma unroll
  for (int i = 0; i < 2; ++i)
#pragma unroll
    for (int j = 0; j < 4; ++j) acc[i][j] = (f32x4){0.f, 0.f, 0.f, 0.f};

  for (int k0 = 0; k0 < D_MODEL; k0 += 32) {
    async_copy16(Ag + k0, Al0);
    async_copy16(Ag + k0 + (size_t)64 * D_MODEL, Al1);
    async_copy16(Bg + k0, Bl);
    __syncthreads();

    bf16x8 af[2], bfr[4];
#pragma unroll
    for (int i = 0; i < 2; ++i)
      af[i] = *(const bf16x8*)&As[(wave * 32 + i * 16 + l15) * 32 + quad * 8];
#pragma unroll
    for (int j = 0; j < 4; ++j)
      bfr[j] = *(const bf16x8*)&Bs[(j * 16 + l15) * 32 + quad * 8];
#pragma unroll
    for (int i = 0; i < 2; ++i)
#pragma unroll
      for (int j = 0; j < 4; ++j)
        acc[i][j] = __builtin_amdgcn_mfma_f32_16x16x32_bf16(af[i], bfr[j],
                                                            acc[i][j], 0, 0, 0);
    __syncthreads();
  }

#pragma unroll
  for (int i = 0; i < 2; ++i) {
    int row = row0 + wave * 32 + i * 16 + quad * 4;
#pragma unroll
    for (int j = 0; j < 4; ++j) {
      int col = nb + j * 16 + l15;
#pragma unroll
      for (int r = 0; r < 4; ++r)
        out[(size_t)(row + r) * D_MODEL + col] = acc[i][j][r];
    }
  }
}

// ---------------------------------------------------------------------------
extern "C" void kernel_launch(void* const* d_in, const int* in_sizes, int n_in,
                              void* d_out, int out_size, void* d_ws, size_t ws_size,
                              hipStream_t stream) {
  const float* X  = (const float*)d_in[0];
  const float* Wq = (const float*)d_in[1];
  const float* Wk = (const float*)d_in[2];
  const float* Wv = (const float*)d_in[3];
  const float* Wo = (const float*)d_in[4];
  const int*  pos = (const int*)d_in[5];
  float* out = (float*)d_out;

  char* w = (char*)d_ws;
  bf16* Xb  = (bf16*)w;  w += (size_t)M_ROWS * D_MODEL * 2;
  bf16* Wqb = (bf16*)w;  w += (size_t)D_MODEL * D_MODEL * 2;
  bf16* Wkb = (bf16*)w;  w += (size_t)D_MODEL * D_MODEL * 2;
  bf16* Wvb = (bf16*)w;  w += (size_t)D_MODEL * D_MODEL * 2;
  bf16* Wob = (bf16*)w;  w += (size_t)D_MODEL * D_MODEL * 2;
  bf16* Qb  = (bf16*)w;  w += (size_t)M_ROWS * D_MODEL * 2;
  bf16* Kb  = (bf16*)w;  w += (size_t)M_ROWS * D_MODEL * 2;
  bf16* VT  = (bf16*)w;  w += (size_t)M_ROWS * D_MODEL * 2;
  bf16* AO  = (bf16*)w;  w += (size_t)M_ROWS * D_MODEL * 2;

  cast_all<<<(NX + 4 * NW) / 256, 256, 0, stream>>>(X, Wq, Wk, Wv, Wo,
                                                    Xb, Wqb, Wkb, Wvb, Wob);
  qkv_gemm<<<dim3(M_ROWS / 128, 3 * D_MODEL / 256), 512, 0, stream>>>(
      Xb, Wqb, Wkb, Wvb, pos, Qb, Kb, VT);
  attn_kernel<<<dim3(B_SZ * NUM_HEADS, T_SZ / 64), 256, 0, stream>>>(
      Qb, Kb, VT, pos, AO);
  out_gemm<<<dim3(M_ROWS / 128, D_MODEL / 64), 256, 0, stream>>>(AO, Wob, out);
}